// Round 13
// baseline (707.846 us; speedup 1.0000x reference)
//
#include <hip/hip_runtime.h>

#define N_NODES  100000
#define NNZ_FEAT 2000000
#define N_EDGES  1600000
#define IN_DIM   256
#define OUT_DIM  64

__device__ __forceinline__ bool keep_entry(float u) {
    // exact replication of reference: floor(0.9f + u) >= 1.0f
    return floorf(0.9f + u) >= 1.0f;
}

// ---------------- A-only CSR build ----------------

// Histogram + per-entry within-row offset (the atomicAdd return). 1.6M
// return-atomics (~25 G/s rate-limited). All return-atomics live here.
__global__ void hist_a(const int* __restrict__ ar,
                       int* __restrict__ cnt_a, int* __restrict__ offs_a) {
    int e = blockIdx.x * blockDim.x + threadIdx.x;
    if (e < N_EDGES) {
        offs_a[e] = atomicAdd(&cnt_a[ar[e]], 1);
    }
}

// 256 threads/block, 4 rows/thread -> 1024 rows/block.
__global__ void scan_pass1(const int* __restrict__ cnt, int* __restrict__ excl,
                           int* __restrict__ bsum, int n) {
    __shared__ int sh[256];
    int t = threadIdx.x;
    int base = blockIdx.x * 1024 + t * 4;
    int v0 = (base + 0 < n) ? cnt[base + 0] : 0;
    int v1 = (base + 1 < n) ? cnt[base + 1] : 0;
    int v2 = (base + 2 < n) ? cnt[base + 2] : 0;
    int v3 = (base + 3 < n) ? cnt[base + 3] : 0;
    int tsum = v0 + v1 + v2 + v3;
    sh[t] = tsum;
    __syncthreads();
    for (int off = 1; off < 256; off <<= 1) {
        int x = (t >= off) ? sh[t - off] : 0;
        __syncthreads();
        sh[t] += x;
        __syncthreads();
    }
    int texcl = sh[t] - tsum;
    if (base + 0 < n) excl[base + 0] = texcl;
    if (base + 1 < n) excl[base + 1] = texcl + v0;
    if (base + 2 < n) excl[base + 2] = texcl + v0 + v1;
    if (base + 3 < n) excl[base + 3] = texcl + v0 + v1 + v2;
    if (t == 255) bsum[blockIdx.x] = sh[255];
}

// one block, 128 threads; nb <= 128
__global__ void scan_pass2(const int* __restrict__ bsum, int* __restrict__ bsumS,
                           int* __restrict__ total, int nb) {
    __shared__ int sh[128];
    int t = threadIdx.x;
    sh[t] = (t < nb) ? bsum[t] : 0;
    __syncthreads();
    int orig = sh[t];
    for (int off = 1; off < 128; off <<= 1) {
        int x = (t >= off) ? sh[t - off] : 0;
        __syncthreads();
        sh[t] += x;
        __syncthreads();
    }
    if (t < nb) bsumS[t] = sh[t] - orig;
    if (t == 127) *total = sh[127];
}

__global__ void scan_pass3(int* __restrict__ startArr, const int* __restrict__ bS,
                           int n) {
    int i = blockIdx.x * blockDim.x + threadIdx.x;
    if (i < n) startArr[i] += bS[i >> 10];
}

// atomic-free A scatter: pos = start[row] + precomputed offset
__global__ void scatter_a(const int* __restrict__ ar, const int* __restrict__ ac,
                          const float* __restrict__ av,
                          const int* __restrict__ startA, const int* __restrict__ offs_a,
                          int2* __restrict__ pkA) {
    int e = blockIdx.x * blockDim.x + threadIdx.x;
    if (e < N_EDGES) {
        int pos = startA[ar[e]] + offs_a[e];
        pkA[pos] = make_int2(__float_as_int(av[e]), ac[e]);
    }
}

// ---------------- SpMM1: direct scatter with POSTED atomics ----------------
// Per kept X entry (r,c,v): h[r, 0..63] += v * W[c, 0..63].
// 64 lanes/entry -> one coalesced 256B atomic RMW burst into L2-resident h.
// unsafeAtomicAdd return unused -> fire-and-forget (no latency chain).
// Duplicate (r,c) entries sum correctly (== segment_sum semantics).
__global__ void spmm1_scatter(const int* __restrict__ xr, const int* __restrict__ xc,
                              const float* __restrict__ xv, const float* __restrict__ du,
                              const float* __restrict__ W, float* __restrict__ h) {
    long long tid = (long long)blockIdx.x * blockDim.x + threadIdx.x;
    int nnz = (int)(tid >> 6);
    int lane = (int)(tid & 63);
    if (nnz >= NNZ_FEAT) return;
    if (!keep_entry(du[nnz])) return;   // wave-uniform (same nnz across wave)
    float v = xv[nnz] * (float)(1.0 / 0.9);
    int r = xr[nnz];
    int c = xc[nnz];
    unsafeAtomicAdd(&h[(size_t)r * OUT_DIM + lane], v * W[c * OUT_DIM + lane]);
}

// ---------------- SpMM2: CSR gather + fused ReLU (8/4/2/1 ILP ladder) -------

__global__ void __launch_bounds__(256) spmm2_csr(
        const int* __restrict__ startArr, const int2* __restrict__ pk,
        const float* __restrict__ h, float* __restrict__ out) {
    int wid  = (blockIdx.x * blockDim.x + threadIdx.x) >> 6;
    int lane = threadIdx.x & 63;
    if (wid >= N_NODES) return;
    int s = startArr[wid], e = startArr[wid + 1];
    float acc = 0.0f;
    int j = s;
    for (; j + 8 <= e; j += 8) {
        int2 p0 = pk[j + 0]; int2 p1 = pk[j + 1];
        int2 p2 = pk[j + 2]; int2 p3 = pk[j + 3];
        int2 p4 = pk[j + 4]; int2 p5 = pk[j + 5];
        int2 p6 = pk[j + 6]; int2 p7 = pk[j + 7];
        float g0 = h[p0.y * OUT_DIM + lane];
        float g1 = h[p1.y * OUT_DIM + lane];
        float g2 = h[p2.y * OUT_DIM + lane];
        float g3 = h[p3.y * OUT_DIM + lane];
        float g4 = h[p4.y * OUT_DIM + lane];
        float g5 = h[p5.y * OUT_DIM + lane];
        float g6 = h[p6.y * OUT_DIM + lane];
        float g7 = h[p7.y * OUT_DIM + lane];
        acc = fmaf(__int_as_float(p0.x), g0, acc);
        acc = fmaf(__int_as_float(p1.x), g1, acc);
        acc = fmaf(__int_as_float(p2.x), g2, acc);
        acc = fmaf(__int_as_float(p3.x), g3, acc);
        acc = fmaf(__int_as_float(p4.x), g4, acc);
        acc = fmaf(__int_as_float(p5.x), g5, acc);
        acc = fmaf(__int_as_float(p6.x), g6, acc);
        acc = fmaf(__int_as_float(p7.x), g7, acc);
    }
    if (j + 4 <= e) {
        int2 p0 = pk[j + 0]; int2 p1 = pk[j + 1];
        int2 p2 = pk[j + 2]; int2 p3 = pk[j + 3];
        float g0 = h[p0.y * OUT_DIM + lane];
        float g1 = h[p1.y * OUT_DIM + lane];
        float g2 = h[p2.y * OUT_DIM + lane];
        float g3 = h[p3.y * OUT_DIM + lane];
        acc = fmaf(__int_as_float(p0.x), g0, acc);
        acc = fmaf(__int_as_float(p1.x), g1, acc);
        acc = fmaf(__int_as_float(p2.x), g2, acc);
        acc = fmaf(__int_as_float(p3.x), g3, acc);
        j += 4;
    }
    if (j + 2 <= e) {
        int2 p0 = pk[j + 0]; int2 p1 = pk[j + 1];
        float g0 = h[p0.y * OUT_DIM + lane];
        float g1 = h[p1.y * OUT_DIM + lane];
        acc = fmaf(__int_as_float(p0.x), g0, acc);
        acc = fmaf(__int_as_float(p1.x), g1, acc);
        j += 2;
    }
    if (j < e) {
        int2 p = pk[j];
        acc = fmaf(__int_as_float(p.x), h[p.y * OUT_DIM + lane], acc);
    }
    out[wid * OUT_DIM + lane] = fmaxf(acc, 0.0f);
}

// ---------------- launch ----------------

extern "C" void kernel_launch(void* const* d_in, const int* in_sizes, int n_in,
                              void* d_out, int out_size, void* d_ws, size_t ws_size,
                              hipStream_t stream) {
    const int*   x_rows       = (const int*)d_in[0];
    const int*   x_cols       = (const int*)d_in[1];
    const float* x_values     = (const float*)d_in[2];
    const int*   adj_rows     = (const int*)d_in[3];
    const int*   adj_cols     = (const int*)d_in[4];
    const float* adj_values   = (const float*)d_in[5];
    const float* drop_uniform = (const float*)d_in[6];
    const float* weights      = (const float*)d_in[7];
    float* out = (float*)d_out;

    // ---- workspace carve (256B-aligned), ~46MB total ----
    char* base = (char*)d_ws;
    size_t off = 0;
    auto carve = [&](size_t bytes) -> void* {
        void* p = base + off;
        off += (bytes + 255) & ~(size_t)255;
        return p;
    };
    float* h       = (float*)carve((size_t)N_NODES * OUT_DIM * sizeof(float)); // 25.6MB
    int*   cnt_a   = (int*)carve(N_NODES * sizeof(int));
    int*   start_a = (int*)carve((N_NODES + 1) * sizeof(int));
    int*   bsum_a  = (int*)carve(128 * sizeof(int));
    int*   bsumS_a = (int*)carve(128 * sizeof(int));
    int*   offs_a  = (int*)carve((size_t)N_EDGES * sizeof(int));    // 6.4MB
    int2*  pk_a    = (int2*)carve((size_t)N_EDGES * sizeof(int2));  // 12.8MB
    (void)ws_size;

    const int NB = (N_NODES + 1023) / 1024;  // 98 scan blocks

    // zero h (accumulator for spmm1 scatter) and A histogram
    hipMemsetAsync(h, 0, (size_t)N_NODES * OUT_DIM * sizeof(float), stream);
    hipMemsetAsync(cnt_a, 0, N_NODES * sizeof(int), stream);

    // A histogram + offset capture (only return-atomics in the pipeline)
    hist_a<<<(N_EDGES + 255) / 256, 256, 0, stream>>>(adj_rows, cnt_a, offs_a);

    // exclusive scan: cnt_a -> start_a
    scan_pass1<<<NB, 256, 0, stream>>>(cnt_a, start_a, bsum_a, N_NODES);
    scan_pass2<<<1, 128, 0, stream>>>(bsum_a, bsumS_a, start_a + N_NODES, NB);
    scan_pass3<<<(N_NODES + 255) / 256, 256, 0, stream>>>(start_a, bsumS_a, N_NODES);

    // atomic-free A scatter into row-sorted packed pairs
    scatter_a<<<(N_EDGES + 255) / 256, 256, 0, stream>>>(
        adj_rows, adj_cols, adj_values, start_a, offs_a, pk_a);

    // SpMM1 by posted-atomic scatter into h (no CSR for X at all)
    {
        long long threads = (long long)NNZ_FEAT * OUT_DIM;  // 128M
        spmm1_scatter<<<(unsigned)((threads + 255) / 256), 256, 0, stream>>>(
            x_rows, x_cols, x_values, drop_uniform, weights, h);
    }

    // SpMM2 gather + fused ReLU
    {
        long long threads = (long long)N_NODES * OUT_DIM;  // 6.4M
        spmm2_csr<<<(unsigned)((threads + 255) / 256), 256, 0, stream>>>(
            start_a, pk_a, h, out);
    }
}